// Round 1
// baseline (223.137 us; speedup 1.0000x reference)
//
#include <hip/hip_runtime.h>
#include <math.h>

#define S_   4096
#define H_   8
#define D_   64
#define HD_  512
#define NCH  256   // chunks per batch
#define LCH  16    // seq steps per chunk
#define RC   128   // rows per chunk = LCH*H_  (h-major: row = h*16 + s)

typedef __bf16 bf16x8 __attribute__((ext_vector_type(8)));
typedef float  f32x4  __attribute__((ext_vector_type(4)));

__device__ __forceinline__ float sigm(float v) { return 1.f / (1.f + __expf(-v)); }

// ---------------- K0: transpose weights to bf16 [n][k] ----------------
__global__ __launch_bounds__(256) void k_wt(const float* __restrict__ Wh,
                                            const float* __restrict__ Wo,
                                            __bf16* __restrict__ Wth,
                                            __bf16* __restrict__ Wto) {
  int idx = blockIdx.x * 256 + threadIdx.x;   // 0..32767
  if (idx < 24576) {
    int k = idx / 192, n = idx % 192;
    Wth[n * 128 + k] = (__bf16)Wh[idx];
  } else {
    int j = idx - 24576;                       // 0..8191, W_og[k][n], n<64
    int k = j >> 6, n = j & 63;
    Wto[n * 128 + k] = (__bf16)Wo[j];
  }
}

// ---------------- K1: per-chunk sums of x ----------------
__global__ __launch_bounds__(512) void k_chunk_sums(const float* __restrict__ x,
                                                    float* __restrict__ sums) {
  const int b = blockIdx.x >> 8, c = blockIdx.x & 255;
  const int t = threadIdx.x;
  const float* p = x + ((size_t)b * S_ + c * LCH) * HD_ + t;
  float acc = 0.f;
  #pragma unroll
  for (int i = 0; i < LCH; ++i) acc += p[(size_t)i * HD_];
  sums[((size_t)b * NCH + c) * HD_ + t] = acc;
}

// ---------------- K2: exclusive scan of chunk sums (in-place, prefetch-8) ----
__global__ __launch_bounds__(512) void k_scan_offsets(float* __restrict__ sums) {
  const int b = blockIdx.x, t = threadIdx.x;
  float run = 0.f;
  for (int c0 = 0; c0 < NCH; c0 += 8) {
    float v[8];
    #pragma unroll
    for (int i = 0; i < 8; ++i)
      v[i] = sums[((size_t)b * NCH + c0 + i) * HD_ + t];
    #pragma unroll
    for (int i = 0; i < 8; ++i) {
      sums[((size_t)b * NCH + c0 + i) * HD_ + t] = run;
      run += v[i];
    }
  }
}

// ---------------- K3: prefix + LayerNorm, emit packed bf16 A = [x | ln] -----
// h-major rows: global row = (b*NCH+c)*128 + h*16 + s
__global__ __launch_bounds__(512) void k_ln(const float* __restrict__ x,
                                            const float* __restrict__ offs,
                                            const float* __restrict__ gamma,
                                            const float* __restrict__ beta,
                                            __bf16* __restrict__ Abf) {
  __shared__ float2 red[2][8];
  const int b = blockIdx.x >> 8, c = blockIdx.x & 255;
  const int t = threadIdx.x;
  float run = offs[((size_t)b * NCH + c) * HD_ + t];
  const float g = gamma[t], be = beta[t];
  const size_t xbase = ((size_t)b * S_ + c * LCH) * HD_ + t;
  const int h = t >> 6, d = t & 63;
  const size_t rbase = ((size_t)b * NCH + c) * 128 + h * 16;
  float xv = x[xbase];
  for (int i = 0; i < LCH; ++i) {
    float xn = (i < LCH - 1) ? x[xbase + (size_t)(i + 1) * HD_] : 0.f;
    float v = run, v2 = run * run;
    #pragma unroll
    for (int o = 32; o; o >>= 1) { v += __shfl_xor(v, o); v2 += __shfl_xor(v2, o); }
    if ((t & 63) == 0) red[i & 1][t >> 6] = make_float2(v, v2);
    __syncthreads();
    float s1 = 0.f, s2 = 0.f;
    #pragma unroll
    for (int w = 0; w < 8; ++w) { s1 += red[i & 1][w].x; s2 += red[i & 1][w].y; }
    float m = s1 * (1.f / HD_);
    float var = fmaf(-m, m, s2 * (1.f / HD_));
    float inv = rsqrtf(var + 1e-5f);
    size_t r = rbase + i;
    Abf[r * 128 + 64 + d] = (__bf16)((run - m) * inv * g + be);
    Abf[r * 128 + d] = (__bf16)xv;
    run += xv;
    xv = xn;
  }
}

// ---------------- K4: gates MFMA GEMM + activations + in-register scan -------
// Block = one chunk: 128 rows (8 h x 16 s, h-major), N=192, K=128. 4 waves.
// No LDS, no barriers. Emits per-row scan prefixes (a,b):
//   cell_row = a_row * cell_chunk_in + b_row
// plus per-chunk totals (cA,cB) for the cross-chunk scan.
__global__ __launch_bounds__(256) void k_gates(const __bf16* __restrict__ Abf,
                                               const __bf16* __restrict__ Wt,
                                               const float* __restrict__ bh,
                                               float* __restrict__ ga,
                                               float* __restrict__ gb,
                                               float* __restrict__ cA,
                                               float* __restrict__ cB) {
  const int t = threadIdx.x;
  const int wave = t >> 6, lane = t & 63;
  const int quad = lane >> 4, l16 = lane & 15;
  const int r0 = blockIdx.x * RC;

  f32x4 acc[2][12];
  #pragma unroll
  for (int i = 0; i < 2; ++i)
    #pragma unroll
    for (int j = 0; j < 12; ++j) acc[i][j] = (f32x4){0.f, 0.f, 0.f, 0.f};

  #pragma unroll
  for (int ks = 0; ks < 4; ++ks) {
    bf16x8 bfrag[12];
    #pragma unroll
    for (int nt = 0; nt < 12; ++nt)
      bfrag[nt] = *(const bf16x8*)(Wt + (nt * 16 + l16) * 128 + ks * 32 + quad * 8);
    #pragma unroll
    for (int mi = 0; mi < 2; ++mi) {
      int mt = wave * 2 + mi;   // mt == h
      bf16x8 afrag = *(const bf16x8*)(Abf + (size_t)(r0 + mt * 16 + l16) * 128 + ks * 32 + quad * 8);
      #pragma unroll
      for (int nt = 0; nt < 12; ++nt)
        acc[mi][nt] = __builtin_amdgcn_mfma_f32_16x16x32_bf16(afrag, bfrag[nt], acc[mi][nt], 0, 0, 0);
    }
  }

  // epilogue: bias+activations, then segmented scan over s (4 regs x 4 quads)
  #pragma unroll
  for (int mi = 0; mi < 2; ++mi) {
    int mt = wave * 2 + mi;     // head h
    #pragma unroll
    for (int nt = 0; nt < 4; ++nt) {
      int dcol = nt * 16 + l16;
      float bi = bh[dcol], bf_ = bh[64 + dcol], bhv = bh[128 + dcol];
      float pa[4], pb[4];
      float a = 1.f, bb = 0.f;
      #pragma unroll
      for (int r = 0; r < 4; ++r) {
        float ip = acc[mi][nt][r] + bi;
        float fp = acc[mi][nt + 4][r] + bf_;
        float hp = acc[mi][nt + 8][r] + bhv;
        float fv = sigm(fp);
        float gv = sigm(ip) * fmaxf(hp, 0.f);
        a = fv * a;                 // local inclusive prefix within quad
        bb = fmaf(fv, bb, gv);
        pa[r] = a; pb[r] = bb;
      }
      // exclusive compose of preceding quads (s-segments) via shuffles
      float exA = 1.f, exB = 0.f;
      #pragma unroll
      for (int q = 0; q < 3; ++q) {
        float Aq = __shfl(a, q * 16 + l16, 64);
        float Bq = __shfl(bb, q * 16 + l16, 64);
        if (q < quad) { exB = fmaf(Aq, exB, Bq); exA = Aq * exA; }
      }
      float ra3 = 0.f, rb3 = 0.f;
      #pragma unroll
      for (int r = 0; r < 4; ++r) {
        float ra = pa[r] * exA;
        float rb = fmaf(pa[r], exB, pb[r]);
        size_t row = (size_t)(r0 + mt * 16 + quad * 4 + r);
        ga[row * 64 + dcol] = ra;
        gb[row * 64 + dcol] = rb;
        ra3 = ra; rb3 = rb;
      }
      if (quad == 3) {   // s = 15: whole-chunk compose totals
        cA[(size_t)blockIdx.x * 512 + mt * 64 + dcol] = ra3;
        cB[(size_t)blockIdx.x * 512 + mt * 64 + dcol] = rb3;
      }
    }
  }
}

// ---------------- K5: cross-chunk scan (in-place: cA becomes cin, prefetch-8) -
__global__ __launch_bounds__(512) void k_cell_scan(float* __restrict__ cA,
                                                   const float* __restrict__ cB,
                                                   const float* __restrict__ initcx) {
  const int b = blockIdx.x, t = threadIdx.x;   // t = h*64+d
  float run = initcx[t];
  for (int c0 = 0; c0 < NCH; c0 += 8) {
    float av[8], bv[8];
    #pragma unroll
    for (int i = 0; i < 8; ++i) {
      size_t idx = ((size_t)b * NCH + c0 + i) * HD_ + t;
      av[i] = cA[idx];
      bv[i] = cB[idx];
    }
    #pragma unroll
    for (int i = 0; i < 8; ++i) {
      size_t idx = ((size_t)b * NCH + c0 + i) * HD_ + t;
      cA[idx] = run;
      run = fmaf(av[i], run, bv[i]);
    }
  }
}

// ---------------- K6: parallel cell-emit + og MFMA GEMM + out = og*cell ------
__global__ __launch_bounds__(256) void k_og(const __bf16* __restrict__ Abf,
                                            const float* __restrict__ ga,
                                            const float* __restrict__ gb,
                                            const float* __restrict__ cin,
                                            const __bf16* __restrict__ Wt,
                                            const float* __restrict__ bo,
                                            float* __restrict__ out) {
  __shared__ float cl[RC * 68];
  const int t = threadIdx.x;
  const int wave = t >> 6, lane = t & 63;
  const int quad = lane >> 4, l16 = lane & 15;
  const int r0 = blockIdx.x * RC;
  const int b4 = blockIdx.x >> 8, c = blockIdx.x & 255;

  // emit cell for this chunk into LDS: cell = a*cin + b (no serial chain)
  #pragma unroll
  for (int mi = 0; mi < 2; ++mi) {
    int mt = wave * 2 + mi;   // head h
    #pragma unroll
    for (int nt = 0; nt < 4; ++nt) {
      int dcol = nt * 16 + l16;
      float ci = cin[(size_t)blockIdx.x * 512 + mt * 64 + dcol];
      #pragma unroll
      for (int r = 0; r < 4; ++r) {
        int rowl = mt * 16 + quad * 4 + r;
        size_t row = (size_t)(r0 + rowl);
        float cv = fmaf(ga[row * 64 + dcol], ci, gb[row * 64 + dcol]);
        cl[rowl * 68 + dcol] = cv;
      }
    }
  }
  __syncthreads();

  f32x4 acc[2][4];
  #pragma unroll
  for (int i = 0; i < 2; ++i)
    #pragma unroll
    for (int j = 0; j < 4; ++j) acc[i][j] = (f32x4){0.f, 0.f, 0.f, 0.f};

  #pragma unroll
  for (int ks = 0; ks < 4; ++ks) {
    bf16x8 bfrag[4];
    #pragma unroll
    for (int nt = 0; nt < 4; ++nt)
      bfrag[nt] = *(const bf16x8*)(Wt + (nt * 16 + l16) * 128 + ks * 32 + quad * 8);
    #pragma unroll
    for (int mi = 0; mi < 2; ++mi) {
      int mt = wave * 2 + mi;
      bf16x8 afrag;
      if (ks < 2) {
        afrag = *(const bf16x8*)(Abf + (size_t)(r0 + mt * 16 + l16) * 128 + ks * 32 + quad * 8);
      } else {
        int rowl = mt * 16 + l16;
        const float* src = &cl[rowl * 68 + (ks - 2) * 32 + quad * 8];
        #pragma unroll
        for (int j = 0; j < 8; ++j) afrag[j] = (__bf16)src[j];
      }
      #pragma unroll
      for (int nt = 0; nt < 4; ++nt)
        acc[mi][nt] = __builtin_amdgcn_mfma_f32_16x16x32_bf16(afrag, bfrag[nt], acc[mi][nt], 0, 0, 0);
    }
  }

  #pragma unroll
  for (int mi = 0; mi < 2; ++mi) {
    int mt = wave * 2 + mi;   // head h
    #pragma unroll
    for (int nt = 0; nt < 4; ++nt) {
      int dcol = nt * 16 + l16;
      float bv = bo[dcol];
      #pragma unroll
      for (int r = 0; r < 4; ++r) {
        int rowl = mt * 16 + quad * 4 + r;
        int s = quad * 4 + r;
        float og = sigm(acc[mi][nt][r] + bv);
        // out is (b, s_global, h, d) with s_global = c*16 + s, h = mt
        out[(((size_t)b4 * S_ + c * LCH + s) * H_ + mt) * 64 + dcol] = og * cl[rowl * 68 + dcol];
      }
    }
  }
}

extern "C" void kernel_launch(void* const* d_in, const int* in_sizes, int n_in,
                              void* d_out, int out_size, void* d_ws, size_t ws_size,
                              hipStream_t stream) {
  const float* x      = (const float*)d_in[0];
  const float* W_hid  = (const float*)d_in[1];
  const float* b_hid  = (const float*)d_in[2];
  const float* W_og   = (const float*)d_in[3];
  const float* b_og   = (const float*)d_in[4];
  const float* gamma  = (const float*)d_in[5];
  const float* beta   = (const float*)d_in[6];
  const float* initcx = (const float*)d_in[7];
  float* out = (float*)d_out;
  float* ws  = (float*)d_ws;

  // ws layout (floats): buf0 0.5M | buf1 0.5M | Abf 8M(bf16 16M) | ga 8M | gb 8M | Wt
  float*  buf0 = ws;                         // sums/offs, then cA/cin
  float*  buf1 = ws + 524288;                // cB
  __bf16* Abf  = (__bf16*)(ws + 1048576);    // [M][128] bf16, h-major rows
  float*  ga   = ws + 1048576 + 8388608;     // per-row scan prefix a
  float*  gb   = ga + 8388608;               // per-row scan prefix b
  __bf16* Wth  = (__bf16*)(gb + 8388608);    // [192][128] bf16
  __bf16* Wto  = Wth + 24576;                // [64][128] bf16

  k_wt          <<<128,  256, 0, stream>>>(W_hid, W_og, Wth, Wto);
  k_chunk_sums  <<<1024, 512, 0, stream>>>(x, buf0);
  k_scan_offsets<<<4,    512, 0, stream>>>(buf0);
  k_ln          <<<1024, 512, 0, stream>>>(x, buf0, gamma, beta, Abf);
  k_gates       <<<1024, 256, 0, stream>>>(Abf, Wth, b_hid, ga, gb, buf0, buf1);
  k_cell_scan   <<<4,    512, 0, stream>>>(buf0, buf1, initcx);
  k_og          <<<1024, 256, 0, stream>>>(Abf, ga, gb, buf0, Wto, b_og, out);
}